// Round 9
// baseline (29.615 us; speedup 1.0000x reference)
//
#include <hip/hip_runtime.h>
#include <math.h>

#define N_ELEM 8388608
#define MLE_EPS 1e-5f
#define BLOCK 256
#define NBLOCKS 2048          // 524288 threads x 16 elements

typedef float f32x4 __attribute__((ext_vector_type(4)));
typedef int   i32x4 __attribute__((ext_vector_type(4)));

// Abramowitz-Stegun 7.1.26 erfc: abs error <= 1.5e-7.
__device__ __forceinline__ float fast_erfc(float x) {
    float ax = __builtin_fabsf(x);
    float t  = __builtin_amdgcn_rcpf(__builtin_fmaf(0.3275911f, ax, 1.0f));
    float p  = 1.061405429f;
    p = __builtin_fmaf(p, t, -1.453152027f);
    p = __builtin_fmaf(p, t,  1.421413741f);
    p = __builtin_fmaf(p, t, -0.284496736f);
    p = __builtin_fmaf(p, t,  0.254829592f);
    p = p * t;
    float e = __expf(-ax * ax);
    float r = p * e;
    return (x < 0.0f) ? (2.0f - r) : r;
}

__device__ __forceinline__ float mle_elem(float mu, float ls, float t, int al) {
    const float inv_sqrt2    = 0.7071067811865476f;
    const float half_log_2pi = 0.9189385332046727f;

    float lx        = __logf(t + MLE_EPS);
    float inv_sigma = __expf(-ls);
    float d         = lx - mu;
    float w         = d * inv_sigma;
    float z         = w * inv_sqrt2;
    float loss_alive = -__logf(__builtin_fmaf(0.5f, fast_erfc(z), MLE_EPS));
    float loss_dead  = lx + ls + half_log_2pi + 0.5f * w * w;
    return al ? loss_alive : loss_dead;
}

// 16 elements/thread. The 16 global_load_dwordx4 are issued from ONE
// asm volatile block: un-rematerializable, un-sinkable -> 256B/lane truly
// in flight (R8 showed the register allocator remats C++ loads back to
// load->use serialization; VGPR stayed 32).
__global__ __launch_bounds__(BLOCK, 4) void mle_partial_kernel(
    const float* __restrict__ pred,
    const float* __restrict__ tte,
    const int*   __restrict__ alive,
    float* __restrict__ partials,
    int n8)
{
    const int tid     = blockIdx.x * BLOCK + threadIdx.x;
    const int nthread = NBLOCKS * BLOCK;          // 524288
    float acc = 0.0f;

    if (n8 == 2 * nthread) {                      // exact fit (N = 8388608)
        const unsigned off_p0 = ((unsigned)tid) << 6;          // 64*i0
        const unsigned off_p1 = off_p0 + (64u * 524288u);      // 64*i1
        const unsigned off_t0 = ((unsigned)tid) << 5;          // 32*i0
        const unsigned off_t1 = off_t0 + (32u * 524288u);      // 32*i1

        f32x4 pa0, pb0, pa1, pb1;   // pred group i0
        f32x4 pa2, pb2, pa3, pb3;   // pred group i1
        f32x4 t0, t1, t2, t3;       // tte
        i32x4 a0, a1, a2, a3;       // alive

        asm volatile(
            "global_load_dwordx4 %0,  %16, %20\n\t"
            "global_load_dwordx4 %1,  %16, %20 offset:16\n\t"
            "global_load_dwordx4 %2,  %16, %20 offset:32\n\t"
            "global_load_dwordx4 %3,  %16, %20 offset:48\n\t"
            "global_load_dwordx4 %4,  %17, %20\n\t"
            "global_load_dwordx4 %5,  %17, %20 offset:16\n\t"
            "global_load_dwordx4 %6,  %17, %20 offset:32\n\t"
            "global_load_dwordx4 %7,  %17, %20 offset:48\n\t"
            "global_load_dwordx4 %8,  %18, %21\n\t"
            "global_load_dwordx4 %9,  %18, %21 offset:16\n\t"
            "global_load_dwordx4 %10, %19, %21\n\t"
            "global_load_dwordx4 %11, %19, %21 offset:16\n\t"
            "global_load_dwordx4 %12, %18, %22\n\t"
            "global_load_dwordx4 %13, %18, %22 offset:16\n\t"
            "global_load_dwordx4 %14, %19, %22\n\t"
            "global_load_dwordx4 %15, %19, %22 offset:16"
            : "=v"(pa0), "=v"(pb0), "=v"(pa1), "=v"(pb1),
              "=v"(pa2), "=v"(pb2), "=v"(pa3), "=v"(pb3),
              "=v"(t0),  "=v"(t1),  "=v"(t2),  "=v"(t3),
              "=v"(a0),  "=v"(a1),  "=v"(a2),  "=v"(a3)
            : "v"(off_p0), "v"(off_p1), "v"(off_t0), "v"(off_t1),
              "s"(pred), "s"(tte), "s"(alive)
            : "memory");

        asm volatile("s_waitcnt vmcnt(0)" ::: "memory");
        __builtin_amdgcn_sched_barrier(0);   // rule #18: no VALU hoisting

        float s0 = 0.0f, s1 = 0.0f;
        s0 += mle_elem(pa0[0], pa0[1], t0[0], a0[0]);
        s1 += mle_elem(pa0[2], pa0[3], t0[1], a0[1]);
        s0 += mle_elem(pb0[0], pb0[1], t0[2], a0[2]);
        s1 += mle_elem(pb0[2], pb0[3], t0[3], a0[3]);
        s0 += mle_elem(pa1[0], pa1[1], t1[0], a1[0]);
        s1 += mle_elem(pa1[2], pa1[3], t1[1], a1[1]);
        s0 += mle_elem(pb1[0], pb1[1], t1[2], a1[2]);
        s1 += mle_elem(pb1[2], pb1[3], t1[3], a1[3]);
        s0 += mle_elem(pa2[0], pa2[1], t2[0], a2[0]);
        s1 += mle_elem(pa2[2], pa2[3], t2[1], a2[1]);
        s0 += mle_elem(pb2[0], pb2[1], t2[2], a2[2]);
        s1 += mle_elem(pb2[2], pb2[3], t2[3], a2[3]);
        s0 += mle_elem(pa3[0], pa3[1], t3[0], a3[0]);
        s1 += mle_elem(pa3[2], pa3[3], t3[1], a3[1]);
        s0 += mle_elem(pb3[0], pb3[1], t3[2], a3[2]);
        s1 += mle_elem(pb3[2], pb3[3], t3[3], a3[3]);
        acc = s0 + s1;
    } else {
        const float4* __restrict__ p4 = (const float4*)pred;
        const float4* __restrict__ t4 = (const float4*)tte;
        const int4*   __restrict__ a4 = (const int4*)alive;
        for (int i = tid; i < n8; i += nthread) {
            float4 pa0 = p4[4 * i + 0];
            float4 pb0 = p4[4 * i + 1];
            float4 pa1 = p4[4 * i + 2];
            float4 pb1 = p4[4 * i + 3];
            float4 t0  = t4[2 * i + 0];
            float4 t1  = t4[2 * i + 1];
            int4   a0  = a4[2 * i + 0];
            int4   a1  = a4[2 * i + 1];
            acc += mle_elem(pa0.x, pa0.y, t0.x, a0.x);
            acc += mle_elem(pa0.z, pa0.w, t0.y, a0.y);
            acc += mle_elem(pb0.x, pb0.y, t0.z, a0.z);
            acc += mle_elem(pb0.z, pb0.w, t0.w, a0.w);
            acc += mle_elem(pa1.x, pa1.y, t1.x, a1.x);
            acc += mle_elem(pa1.z, pa1.w, t1.y, a1.y);
            acc += mle_elem(pb1.x, pb1.y, t1.z, a1.z);
            acc += mle_elem(pb1.z, pb1.w, t1.w, a1.w);
        }
    }

    #pragma unroll
    for (int off = 32; off > 0; off >>= 1)
        acc += __shfl_down(acc, off);

    __shared__ float wsum[BLOCK / 64];
    if ((threadIdx.x & 63) == 0) wsum[threadIdx.x >> 6] = acc;
    __syncthreads();
    if (threadIdx.x == 0) {
        float s = 0.0f;
        #pragma unroll
        for (int w = 0; w < BLOCK / 64; ++w) s += wsum[w];
        partials[blockIdx.x] = s;
    }
}

__global__ __launch_bounds__(BLOCK) void mle_final_kernel(
    const float4* __restrict__ partials4, float* __restrict__ out)
{
    float acc = 0.0f;
    #pragma unroll
    for (int k = 0; k < 2; ++k) {
        float4 v = partials4[threadIdx.x + k * BLOCK];
        acc += (v.x + v.y) + (v.z + v.w);
    }

    #pragma unroll
    for (int off = 32; off > 0; off >>= 1)
        acc += __shfl_down(acc, off);

    __shared__ float wsum[BLOCK / 64];
    if ((threadIdx.x & 63) == 0) wsum[threadIdx.x >> 6] = acc;
    __syncthreads();
    if (threadIdx.x == 0) {
        float s = 0.0f;
        #pragma unroll
        for (int w = 0; w < BLOCK / 64; ++w) s += wsum[w];
        out[0] = s / (float)N_ELEM;
    }
}

extern "C" void kernel_launch(void* const* d_in, const int* in_sizes, int n_in,
                              void* d_out, int out_size, void* d_ws, size_t ws_size,
                              hipStream_t stream) {
    const float* pred  = (const float*)d_in[0];
    const float* tte   = (const float*)d_in[1];
    const int*   alive = (const int*)d_in[2];
    float* out = (float*)d_out;
    float* partials = (float*)d_ws;

    const int n  = in_sizes[1];
    const int n8 = n >> 3;

    mle_partial_kernel<<<NBLOCKS, BLOCK, 0, stream>>>(pred, tte, alive, partials, n8);
    mle_final_kernel<<<1, BLOCK, 0, stream>>>((const float4*)partials, out);
}

// Round 10
// 28.312 us; speedup vs baseline: 1.0460x; 1.0460x over previous
//
#include <hip/hip_runtime.h>
#include <math.h>

#define N_ELEM 8388608
#define MLE_EPS 1e-5f
#define BLOCK 256
#define NBLOCKS 2048          // 524288 threads x 16 elements

// Abramowitz-Stegun 7.1.26 erfc: abs error <= 1.5e-7.
__device__ __forceinline__ float fast_erfc(float x) {
    float ax = __builtin_fabsf(x);
    float t  = __builtin_amdgcn_rcpf(__builtin_fmaf(0.3275911f, ax, 1.0f));
    float p  = 1.061405429f;
    p = __builtin_fmaf(p, t, -1.453152027f);
    p = __builtin_fmaf(p, t,  1.421413741f);
    p = __builtin_fmaf(p, t, -0.284496736f);
    p = __builtin_fmaf(p, t,  0.254829592f);
    p = p * t;
    float e = __expf(-ax * ax);
    float r = p * e;
    return (x < 0.0f) ? (2.0f - r) : r;
}

__device__ __forceinline__ float mle_elem(float mu, float ls, float t, int al) {
    const float inv_sqrt2    = 0.7071067811865476f;
    const float half_log_2pi = 0.9189385332046727f;

    float lx        = __logf(t + MLE_EPS);
    float inv_sigma = __expf(-ls);
    float d         = lx - mu;
    float w         = d * inv_sigma;
    float z         = w * inv_sqrt2;
    float loss_alive = -__logf(__builtin_fmaf(0.5f, fast_erfc(z), MLE_EPS));
    float loss_dead  = lx + ls + half_log_2pi + 0.5f * w * w;
    return al ? loss_alive : loss_dead;
}

// Pair-dense layout: pair j = elements (2j, 2j+1).
//   pred float4[j] = (mu_2j, ls_2j, mu_2j+1, ls_2j+1)  -> 16B/lane, DENSE
//   tte  float2[j] = (t_2j, t_2j+1)                    ->  8B/lane, DENSE
//   alive  int2[j] = (a_2j, a_2j+1)                    ->  8B/lane, DENSE
// Every wave-level load instruction is lane-contiguous (R5-R9 were 2-4x
// strided within each instruction -> TA split them, ~10 B/cyc/CU plateau).
// Element->lane mapping is arbitrary for a sum, so no shuffles needed.
__global__ __launch_bounds__(BLOCK, 4) void mle_partial_kernel(
    const float* __restrict__ pred,
    const float* __restrict__ tte,
    const int*   __restrict__ alive,
    float* __restrict__ partials,
    int n2)   // number of pairs (N/2 = 4M)
{
    const float4* __restrict__ p4 = (const float4*)pred;
    const float2* __restrict__ t2 = (const float2*)tte;
    const int2*   __restrict__ a2 = (const int2*)alive;

    const int g  = blockIdx.x * BLOCK + threadIdx.x;
    const int NT = NBLOCKS * BLOCK;               // 524288
    float acc = 0.0f;

    if (n2 == 8 * NT) {                           // exact fit (N = 8388608)
        #pragma unroll
        for (int r = 0; r < 8; ++r) {
            const int j = g + r * NT;
            float4 p = p4[j];
            float2 t = t2[j];
            int2   a = a2[j];
            acc += mle_elem(p.x, p.y, t.x, a.x);
            acc += mle_elem(p.z, p.w, t.y, a.y);
        }
    } else {
        for (int j = g; j < n2; j += NT) {
            float4 p = p4[j];
            float2 t = t2[j];
            int2   a = a2[j];
            acc += mle_elem(p.x, p.y, t.x, a.x);
            acc += mle_elem(p.z, p.w, t.y, a.y);
        }
    }

    #pragma unroll
    for (int off = 32; off > 0; off >>= 1)
        acc += __shfl_down(acc, off);

    __shared__ float wsum[BLOCK / 64];
    if ((threadIdx.x & 63) == 0) wsum[threadIdx.x >> 6] = acc;
    __syncthreads();
    if (threadIdx.x == 0) {
        float s = 0.0f;
        #pragma unroll
        for (int w = 0; w < BLOCK / 64; ++w) s += wsum[w];
        partials[blockIdx.x] = s;
    }
}

__global__ __launch_bounds__(BLOCK) void mle_final_kernel(
    const float4* __restrict__ partials4, float* __restrict__ out)
{
    float acc = 0.0f;
    #pragma unroll
    for (int k = 0; k < 2; ++k) {
        float4 v = partials4[threadIdx.x + k * BLOCK];
        acc += (v.x + v.y) + (v.z + v.w);
    }

    #pragma unroll
    for (int off = 32; off > 0; off >>= 1)
        acc += __shfl_down(acc, off);

    __shared__ float wsum[BLOCK / 64];
    if ((threadIdx.x & 63) == 0) wsum[threadIdx.x >> 6] = acc;
    __syncthreads();
    if (threadIdx.x == 0) {
        float s = 0.0f;
        #pragma unroll
        for (int w = 0; w < BLOCK / 64; ++w) s += wsum[w];
        out[0] = s / (float)N_ELEM;
    }
}

extern "C" void kernel_launch(void* const* d_in, const int* in_sizes, int n_in,
                              void* d_out, int out_size, void* d_ws, size_t ws_size,
                              hipStream_t stream) {
    const float* pred  = (const float*)d_in[0];
    const float* tte   = (const float*)d_in[1];
    const int*   alive = (const int*)d_in[2];
    float* out = (float*)d_out;
    float* partials = (float*)d_ws;

    const int n  = in_sizes[1];
    const int n2 = n >> 1;   // 4M pairs

    mle_partial_kernel<<<NBLOCKS, BLOCK, 0, stream>>>(pred, tte, alive, partials, n2);
    mle_final_kernel<<<1, BLOCK, 0, stream>>>((const float4*)partials, out);
}